// Round 6
// baseline (363.157 us; speedup 1.0000x reference)
//
#include <hip/hip_runtime.h>

// ObjectRelationNetwork on MI355X — barrier-free main loop + FULL-LINE store epilogue.
//
// History: r0 (barriers, 2blk/CU) orn~155us; r5 (barrier-free, 3blk/CU, NT f32x4)
// orn~150us. Both 3.5x the 40us write roofline -> shared bottleneck. Both write e
// in 64B runs per row (quad*16B). H1: partial-128B-line writes degrade the HBM
// write path (~1.7 TB/s effective). This round: per-wave LDS transpose staging
// (stride-66 dwords; write <=4-way b64, read 2-way free) -> 256B-contiguous,
// line-aligned dwordx4 stores (4 full rows per inst). No barriers added (same-wave
// lgkmcnt only). LDS 49.7KB -> still 3 blk/CU.
// RNE f2bf everywhere (r2: cvt_pk asm gave absmax 0.407 vs 0.016).

typedef __attribute__((ext_vector_type(8))) short bf16x8;   // 8 bf16 = 4 VGPRs
typedef __attribute__((ext_vector_type(4))) float f32x4;    // MFMA C/D, nt stores
typedef __attribute__((ext_vector_type(2))) float f32x2;    // b64 LDS accesses
typedef __attribute__((ext_vector_type(4))) unsigned u32x4;
typedef __attribute__((ext_vector_type(2))) unsigned u32x2;

#define MFMA16(a, b, c) __builtin_amdgcn_mfma_f32_16x16x32_bf16((a), (b), (c), 0, 0, 0)
#define E_ELEMS 62914560ull   // 240*1024*256 e floats, then 245760 all_is_obj floats

__device__ __forceinline__ short f2bf(float f) {          // RNE float->bf16
  unsigned u = __builtin_bit_cast(unsigned, f);
  u += 0x7fffu + ((u >> 16) & 1u);
  return (short)(u >> 16);
}
__device__ __forceinline__ unsigned pack2(short lo, short hi) {
  return (unsigned)(unsigned short)lo | ((unsigned)(unsigned short)hi << 16);
}

// h-fragment: relu(u+v) elementwise on 8 bf16, repacked to bf16 (RNE).
__device__ __forceinline__ bf16x8 hfrag2(bf16x8 u, bf16x8 v) {
  u32x4 uu = __builtin_bit_cast(u32x4, u);
  u32x4 vv = __builtin_bit_cast(u32x4, v);
  u32x4 r;
#pragma unroll
  for (int k = 0; k < 4; k++) {
    float lo = __builtin_bit_cast(float, uu[k] << 16) +
               __builtin_bit_cast(float, vv[k] << 16);
    float hi = __builtin_bit_cast(float, uu[k] & 0xffff0000u) +
               __builtin_bit_cast(float, vv[k] & 0xffff0000u);
    r[k] = pack2(f2bf(fmaxf(lo, 0.f)), f2bf(fmaxf(hi, 0.f)));
  }
  return __builtin_bit_cast(bf16x8, r);
}

// ---- prep: W2 (256x256) -> W2L[kb=k>>3][n][k&7]  (K=256, fragment layout)
//            W1 (256x256) -> W1L[part][kb][n][jj]  (part 0: d 0..127 (U),
//                                                   part 1: d 128..255 (V))
__global__ void prep_weights(const float* __restrict__ W2, const float* __restrict__ W1,
                             short* __restrict__ W2L, short* __restrict__ W1L) {
  int t = blockIdx.x * 256 + threadIdx.x;   // 0..16383
  const float* src;
  short* dst;
  if (t < 8192) {
    int kb = t >> 8, n = t & 255;
    src = W2 + (size_t)n * 256 + kb * 8;
    dst = W2L + (size_t)t * 8;
  } else {
    int u = t - 8192;                       // 0..8191
    int part = u >> 12, kb = (u >> 8) & 15, n = u & 255;
    src = W1 + (size_t)n * 256 + part * 128 + kb * 8;
    dst = W1L + (size_t)u * 8;
  }
  float4 x = *(const float4*)src;
  float4 y = *(const float4*)(src + 4);
  bf16x8 f;
  f[0] = f2bf(x.x); f[1] = f2bf(x.y); f[2] = f2bf(x.z); f[3] = f2bf(x.w);
  f[4] = f2bf(y.x); f[5] = f2bf(y.y); f[6] = f2bf(y.z); f[7] = f2bf(y.w);
  *(bf16x8*)dst = f;
}

// ---- main: 960 blocks (4 per (b,t)), 256 threads. LDS 49.7 KB; 3 blocks/CU.
__global__ __launch_bounds__(256, 3) void orn_main(
    const float* __restrict__ objs, const float* __restrict__ b1,
    const float* __restrict__ b2, const short* __restrict__ W1L,
    const short* __restrict__ W2L, float* __restrict__ out) {
  __shared__ short ULs[32 * 32 * 8];   // [kb=o>>3][i][o&7]  bf16 of U' = O@W1a^T + b1
  __shared__ short VLs[32 * 32 * 8];   // [kb][j][jj]        bf16 of V  = O@W1b^T
  __shared__ float stage[4 * 16 * 66]; // per-wave 16x64 f32 transpose tile, stride 66

  float* psum  = (float*)ULs;          // phase-1 scratch aliases (dead after sync3)
  float* fclip = (float*)VLs;

  const int tid = threadIdx.x;
  const int bid = blockIdx.x;
  const int bt  = bid >> 2;            // 0..239
  const int q   = bid & 3;             // row-quarter of this (b,t) slab
  const int b   = bt / 15;
  const int tm  = bt - b * 15;         // t-1
  const float* O = objs + (size_t)(b * 16 + tm + 1) * (32 * 128);

  const int lane = tid & 63;
  const int w    = tid >> 6;           // wave 0..3
  const int l15  = lane & 15;
  const int quad = lane >> 4;
  const int n0   = w * 64;             // this wave's o-col base (N split 4x64)

  // ---------------- Phase 1: fp32 row sums -> all_is_obj ----------------
  {
    int i = tid >> 3, c = tid & 7;
    const float* p = O + i * 128 + c * 16;
    float s = 0.f;
#pragma unroll
    for (int e = 0; e < 4; e++) {
      float4 v = *(const float4*)(p + e * 4);
      s += v.x + v.y + v.z + v.w;
    }
    psum[tid] = s;
  }
  __syncthreads();                     // sync1
  if (tid < 32) {
    float s = 0.f;
#pragma unroll
    for (int c = 0; c < 8; c++) s += psum[tid * 8 + c];
    fclip[tid] = fminf(fmaxf(s, 0.f), 1.f);
  }
  __syncthreads();                     // sync2
  {
    int p = q * 256 + tid;             // this WG's 256 pairs
    int i = p >> 5, j = p & 31;
    float v = fclip[i] * fclip[j] * (float)(tm + 1);
    out[E_ELEMS + (size_t)bt * 1024 + p] = fminf(fmaxf(v, 0.f), 1.f);
  }

  // ------- Phase 2: U',V (32 objs x 256 hidden) via MFMA, swapped operands -------
  // A = W1L (M = o rows), B = O (N = i cols).  D: row=quad*4+r -> o, col=l15 -> i.
  {
    // B-fragments from O: B[k = ks*32+quad*8+jj][i = ni*16+l15]
    bf16x8 bfr[2][4];
#pragma unroll
    for (int ni = 0; ni < 2; ni++)
#pragma unroll
      for (int ks = 0; ks < 4; ks++) {
        const float* p = O + (ni * 16 + l15) * 128 + ks * 32 + quad * 8;
        float4 x = *(const float4*)p;
        float4 y = *(const float4*)(p + 4);
        bf16x8 f;
        f[0] = f2bf(x.x); f[1] = f2bf(x.y); f[2] = f2bf(x.z); f[3] = f2bf(x.w);
        f[4] = f2bf(y.x); f[5] = f2bf(y.y); f[6] = f2bf(y.z); f[7] = f2bf(y.w);
        bfr[ni][ks] = f;
      }
    const f32x4 zf = {0.f, 0.f, 0.f, 0.f};
    f32x4 aU[4][2], aV[4][2];
#pragma unroll
    for (int ms = 0; ms < 4; ms++)
#pragma unroll
      for (int ni = 0; ni < 2; ni++) { aU[ms][ni] = zf; aV[ms][ni] = zf; }
#pragma unroll
    for (int ks = 0; ks < 4; ks++) {
      const int kb = ks * 4 + quad;    // 0..15 (K=128 per part)
#pragma unroll
      for (int ms = 0; ms < 4; ms++) {
        const int n = n0 + ms * 16 + l15;
        bf16x8 au = *(const bf16x8*)&W1L[(size_t)((kb << 8) + n) * 8];
        bf16x8 av = *(const bf16x8*)&W1L[(size_t)(4096 + (kb << 8) + n) * 8];
#pragma unroll
        for (int ni = 0; ni < 2; ni++) {
          aU[ms][ni] = MFMA16(au, bfr[ni][ks], aU[ms][ni]);
          aV[ms][ni] = MFMA16(av, bfr[ni][ks], aV[ms][ni]);
        }
      }
    }
    __syncthreads();                   // sync3: psum/fclip reads done, safe to overwrite
    // write-out: lane holds o = n0+ms*16+quad*4+r (r consecutive!), i = ni*16+l15
#pragma unroll
    for (int ms = 0; ms < 4; ms++) {
      const int ob = n0 + ms * 16 + quad * 4;
      const float4 bb = *(const float4*)&b1[ob];      // fold b1 into U'
      const int kb = ob >> 3, jo = ob & 7;            // jo in {0,4} -> 8B-aligned
#pragma unroll
      for (int ni = 0; ni < 2; ni++) {
        const int i = ni * 16 + l15;
        u32x2 uu, vv;
        uu[0] = pack2(f2bf(aU[ms][ni][0] + bb.x), f2bf(aU[ms][ni][1] + bb.y));
        uu[1] = pack2(f2bf(aU[ms][ni][2] + bb.z), f2bf(aU[ms][ni][3] + bb.w));
        vv[0] = pack2(f2bf(aV[ms][ni][0]), f2bf(aV[ms][ni][1]));
        vv[1] = pack2(f2bf(aV[ms][ni][2]), f2bf(aV[ms][ni][3]));
        *(u32x2*)&ULs[((kb << 5) + i) * 8 + jo] = uu;
        *(u32x2*)&VLs[((kb << 5) + i) * 8 + jo] = vv;
      }
    }
  }
  __syncthreads();                     // sync4: ULs/VLs ready; NO barriers after this

  // ------------- Main loop: e = relu(h @ W2^T + b2), barrier-free -------------
  // A = W2L (M = o), B = h built in-register. D: row -> o (4 consec per lane), col -> p.
  const int R0 = q * 256;
  const f32x4 zf = {0.f, 0.f, 0.f, 0.f};
  float* const wstage = stage + w * (16 * 66);   // this wave's private transpose tile
#pragma unroll 1
  for (int c = 0; c < 4; c++) {        // 4 chunks of 64 pair-rows
    f32x4 acc[4][4];                   // [ms=o-tile][ns=pair-tile]
#pragma unroll
    for (int ms = 0; ms < 4; ms++)
#pragma unroll
      for (int ns = 0; ns < 4; ns++) acc[ms][ns] = zf;
    const int i0 = q * 8 + c * 2;      // two i-values this chunk: i0, i0+1
#pragma unroll 1
    for (int ks = 0; ks < 8; ks++) {   // unroll 1: keep live set under the 168 cap
      const int kb = ks * 4 + quad;    // 0..31 (K=256)
      const bf16x8 a0 = *(const bf16x8*)&W2L[(size_t)((kb << 8) + n0      + l15) * 8];
      const bf16x8 a1 = *(const bf16x8*)&W2L[(size_t)((kb << 8) + n0 + 16 + l15) * 8];
      const bf16x8 a2 = *(const bf16x8*)&W2L[(size_t)((kb << 8) + n0 + 32 + l15) * 8];
      const bf16x8 a3 = *(const bf16x8*)&W2L[(size_t)((kb << 8) + n0 + 48 + l15) * 8];
      const bf16x8 u0 = *(const bf16x8*)&ULs[((kb << 5) + i0    ) * 8];  // quad-bcast
      const bf16x8 u1 = *(const bf16x8*)&ULs[((kb << 5) + i0 + 1) * 8];
      const bf16x8 v0 = *(const bf16x8*)&VLs[((kb << 5) + l15     ) * 8]; // 256B runs
      const bf16x8 v1 = *(const bf16x8*)&VLs[((kb << 5) + 16 + l15) * 8];
      {
        const bf16x8 hb = hfrag2(u0, v0);   // ns=0: pairs (i0, j=l15)
        acc[0][0] = MFMA16(a0, hb, acc[0][0]);
        acc[1][0] = MFMA16(a1, hb, acc[1][0]);
        acc[2][0] = MFMA16(a2, hb, acc[2][0]);
        acc[3][0] = MFMA16(a3, hb, acc[3][0]);
      }
      {
        const bf16x8 hb = hfrag2(u1, v0);   // ns=2: (i0+1, l15)
        acc[0][2] = MFMA16(a0, hb, acc[0][2]);
        acc[1][2] = MFMA16(a1, hb, acc[1][2]);
        acc[2][2] = MFMA16(a2, hb, acc[2][2]);
        acc[3][2] = MFMA16(a3, hb, acc[3][2]);
      }
      {
        const bf16x8 hb = hfrag2(u0, v1);   // ns=1: (i0, 16+l15)
        acc[0][1] = MFMA16(a0, hb, acc[0][1]);
        acc[1][1] = MFMA16(a1, hb, acc[1][1]);
        acc[2][1] = MFMA16(a2, hb, acc[2][1]);
        acc[3][1] = MFMA16(a3, hb, acc[3][1]);
      }
      {
        const bf16x8 hb = hfrag2(u1, v1);   // ns=3: (i0+1, 16+l15)
        acc[0][3] = MFMA16(a0, hb, acc[0][3]);
        acc[1][3] = MFMA16(a1, hb, acc[1][3]);
        acc[2][3] = MFMA16(a2, hb, acc[2][3]);
        acc[3][3] = MFMA16(a3, hb, acc[3][3]);
      }
    }

    // epilogue: bias+relu -> per-wave LDS transpose -> FULL-LINE 256B-run stores.
    // write: row=l15 (stride 66 dw), col=ms*16+quad*4+r  (b64 pairs, <=4-way)
    // read : row=p*4+quad, 4 floats at col l15*4        (b64 pairs, 2-way free)
    // store: 4 rows x 256B contiguous per inst, 128B-line aligned
    const size_t prow = (size_t)bt * 1024 + R0 + c * 64;
#pragma unroll 1
    for (int ns = 0; ns < 4; ns++) {
#pragma unroll
      for (int ms = 0; ms < 4; ms++) {
        const int o = n0 + ms * 16 + quad * 4;
        const float4 bb = *(const float4*)&b2[o];
        float* sp = wstage + l15 * 66 + ms * 16 + quad * 4;
        f32x2 w01, w23;
        w01[0] = fmaxf(acc[ms][ns][0] + bb.x, 0.f);
        w01[1] = fmaxf(acc[ms][ns][1] + bb.y, 0.f);
        w23[0] = fmaxf(acc[ms][ns][2] + bb.z, 0.f);
        w23[1] = fmaxf(acc[ms][ns][3] + bb.w, 0.f);
        *(f32x2*)sp = w01;
        *(f32x2*)(sp + 2) = w23;
      }
#pragma unroll
      for (int p = 0; p < 4; p++) {
        const float* rp = wstage + (p * 4 + quad) * 66 + l15 * 4;
        f32x2 lo = *(const f32x2*)rp;
        f32x2 hi = *(const f32x2*)(rp + 2);
        f32x4 rv;
        rv[0] = lo[0]; rv[1] = lo[1]; rv[2] = hi[0]; rv[3] = hi[1];
        float* po = out + (prow + ns * 16 + p * 4 + quad) * 256 + n0 + l15 * 4;
        __builtin_nontemporal_store(rv, (f32x4*)po);
      }
    }
  }
}

extern "C" void kernel_launch(void* const* d_in, const int* in_sizes, int n_in,
                              void* d_out, int out_size, void* d_ws, size_t ws_size,
                              hipStream_t stream) {
  const float* objs = (const float*)d_in[0];
  const float* W1   = (const float*)d_in[1];
  const float* b1   = (const float*)d_in[2];
  const float* W2   = (const float*)d_in[3];
  const float* b2   = (const float*)d_in[4];
  float* out = (float*)d_out;
  short* W2L = (short*)d_ws;                 // 128 KB bf16 swizzled W2
  short* W1L = W2L + 8192 * 8;               // 128 KB bf16 swizzled W1 (U|V parts)

  prep_weights<<<64, 256, 0, stream>>>(W2, W1, W2L, W1L);
  orn_main<<<960, 256, 0, stream>>>(objs, b1, b2, W1L, W2L, out);
}

// Round 7
// 315.291 us; speedup vs baseline: 1.1518x; 1.1518x over previous
//
#include <hip/hip_runtime.h>

// ObjectRelationNetwork on MI355X — barrier-free main loop + W2L prefetch pipeline.
//
// r6 counters (first clean orn_main profile): 156.6us steady, MfmaUtil 9%, VALUBusy
// 35%, occupancy 25%, WRITE 464MB (ideal 253!), FETCH 78MB (ideal ~12). Diagnosis:
// (a) r6's "#pragma unroll 1 for ns" epilogue runtime-indexed acc -> scratch spill
//     around epilogue = the +211MB write / +66MB fetch (rule #20).
// (b) kernel is LATENCY-stalled (all pipes <45%): 4x W2L global loads (L2 ~250cy)
//     per ks-iter on the critical path, unroll 1, only 3 waves/SIMD.
// Fix: (1) r5 fully-unrolled direct NT-store epilogue (no runtime acc indexing,
// LDS back to 32KB); (2) explicit one-iteration prefetch of W2L fragments
// (pa0..pa3), wrap-around covers chunk boundaries. Live set ~140 < cap 170.
// RNE f2bf everywhere (r2: cvt_pk asm absmax 0.407 vs 0.016).

typedef __attribute__((ext_vector_type(8))) short bf16x8;   // 8 bf16 = 4 VGPRs
typedef __attribute__((ext_vector_type(4))) float f32x4;    // MFMA C/D, nt stores
typedef __attribute__((ext_vector_type(4))) unsigned u32x4;
typedef __attribute__((ext_vector_type(2))) unsigned u32x2;

#define MFMA16(a, b, c) __builtin_amdgcn_mfma_f32_16x16x32_bf16((a), (b), (c), 0, 0, 0)
#define E_ELEMS 62914560ull   // 240*1024*256 e floats, then 245760 all_is_obj floats

__device__ __forceinline__ short f2bf(float f) {          // RNE float->bf16
  unsigned u = __builtin_bit_cast(unsigned, f);
  u += 0x7fffu + ((u >> 16) & 1u);
  return (short)(u >> 16);
}
__device__ __forceinline__ unsigned pack2(short lo, short hi) {
  return (unsigned)(unsigned short)lo | ((unsigned)(unsigned short)hi << 16);
}

// h-fragment: relu(u+v) elementwise on 8 bf16, repacked to bf16 (RNE).
__device__ __forceinline__ bf16x8 hfrag2(bf16x8 u, bf16x8 v) {
  u32x4 uu = __builtin_bit_cast(u32x4, u);
  u32x4 vv = __builtin_bit_cast(u32x4, v);
  u32x4 r;
#pragma unroll
  for (int k = 0; k < 4; k++) {
    float lo = __builtin_bit_cast(float, uu[k] << 16) +
               __builtin_bit_cast(float, vv[k] << 16);
    float hi = __builtin_bit_cast(float, uu[k] & 0xffff0000u) +
               __builtin_bit_cast(float, vv[k] & 0xffff0000u);
    r[k] = pack2(f2bf(fmaxf(lo, 0.f)), f2bf(fmaxf(hi, 0.f)));
  }
  return __builtin_bit_cast(bf16x8, r);
}

// ---- prep: W2 (256x256) -> W2L[kb=k>>3][n][k&7]  (K=256, fragment layout)
//            W1 (256x256) -> W1L[part][kb][n][jj]  (part 0: d 0..127 (U),
//                                                   part 1: d 128..255 (V))
__global__ void prep_weights(const float* __restrict__ W2, const float* __restrict__ W1,
                             short* __restrict__ W2L, short* __restrict__ W1L) {
  int t = blockIdx.x * 256 + threadIdx.x;   // 0..16383
  const float* src;
  short* dst;
  if (t < 8192) {
    int kb = t >> 8, n = t & 255;
    src = W2 + (size_t)n * 256 + kb * 8;
    dst = W2L + (size_t)t * 8;
  } else {
    int u = t - 8192;                       // 0..8191
    int part = u >> 12, kb = (u >> 8) & 15, n = u & 255;
    src = W1 + (size_t)n * 256 + part * 128 + kb * 8;
    dst = W1L + (size_t)u * 8;
  }
  float4 x = *(const float4*)src;
  float4 y = *(const float4*)(src + 4);
  bf16x8 f;
  f[0] = f2bf(x.x); f[1] = f2bf(x.y); f[2] = f2bf(x.z); f[3] = f2bf(x.w);
  f[4] = f2bf(y.x); f[5] = f2bf(y.y); f[6] = f2bf(y.z); f[7] = f2bf(y.w);
  *(bf16x8*)dst = f;
}

// ---- main: 960 blocks (4 per (b,t)), 256 threads. LDS 32 KB; 3 blocks/CU.
__global__ __launch_bounds__(256, 3) void orn_main(
    const float* __restrict__ objs, const float* __restrict__ b1,
    const float* __restrict__ b2, const short* __restrict__ W1L,
    const short* __restrict__ W2L, float* __restrict__ out) {
  __shared__ short ULs[32 * 32 * 8];   // [kb=o>>3][i][o&7]  bf16 of U' = O@W1a^T + b1
  __shared__ short VLs[32 * 32 * 8];   // [kb][j][jj]        bf16 of V  = O@W1b^T

  float* psum  = (float*)ULs;          // phase-1 scratch aliases (dead after sync3)
  float* fclip = (float*)VLs;

  const int tid = threadIdx.x;
  const int bid = blockIdx.x;
  const int bt  = bid >> 2;            // 0..239
  const int q   = bid & 3;             // row-quarter of this (b,t) slab
  const int b   = bt / 15;
  const int tm  = bt - b * 15;         // t-1
  const float* O = objs + (size_t)(b * 16 + tm + 1) * (32 * 128);

  const int lane = tid & 63;
  const int w    = tid >> 6;           // wave 0..3
  const int l15  = lane & 15;
  const int quad = lane >> 4;
  const int n0   = w * 64;             // this wave's o-col base (N split 4x64)

  // ---------------- Phase 1: fp32 row sums -> all_is_obj ----------------
  {
    int i = tid >> 3, c = tid & 7;
    const float* p = O + i * 128 + c * 16;
    float s = 0.f;
#pragma unroll
    for (int e = 0; e < 4; e++) {
      float4 v = *(const float4*)(p + e * 4);
      s += v.x + v.y + v.z + v.w;
    }
    psum[tid] = s;
  }
  __syncthreads();                     // sync1
  if (tid < 32) {
    float s = 0.f;
#pragma unroll
    for (int c = 0; c < 8; c++) s += psum[tid * 8 + c];
    fclip[tid] = fminf(fmaxf(s, 0.f), 1.f);
  }
  __syncthreads();                     // sync2
  {
    int p = q * 256 + tid;             // this WG's 256 pairs
    int i = p >> 5, j = p & 31;
    float v = fclip[i] * fclip[j] * (float)(tm + 1);
    out[E_ELEMS + (size_t)bt * 1024 + p] = fminf(fmaxf(v, 0.f), 1.f);
  }

  // ------- Phase 2: U',V (32 objs x 256 hidden) via MFMA, swapped operands -------
  // A = W1L (M = o rows), B = O (N = i cols).  D: row=quad*4+r -> o, col=l15 -> i.
  {
    // B-fragments from O: B[k = ks*32+quad*8+jj][i = ni*16+l15]
    bf16x8 bfr[2][4];
#pragma unroll
    for (int ni = 0; ni < 2; ni++)
#pragma unroll
      for (int ks = 0; ks < 4; ks++) {
        const float* p = O + (ni * 16 + l15) * 128 + ks * 32 + quad * 8;
        float4 x = *(const float4*)p;
        float4 y = *(const float4*)(p + 4);
        bf16x8 f;
        f[0] = f2bf(x.x); f[1] = f2bf(x.y); f[2] = f2bf(x.z); f[3] = f2bf(x.w);
        f[4] = f2bf(y.x); f[5] = f2bf(y.y); f[6] = f2bf(y.z); f[7] = f2bf(y.w);
        bfr[ni][ks] = f;
      }
    const f32x4 zf = {0.f, 0.f, 0.f, 0.f};
    f32x4 aU[4][2], aV[4][2];
#pragma unroll
    for (int ms = 0; ms < 4; ms++)
#pragma unroll
      for (int ni = 0; ni < 2; ni++) { aU[ms][ni] = zf; aV[ms][ni] = zf; }
#pragma unroll
    for (int ks = 0; ks < 4; ks++) {
      const int kb = ks * 4 + quad;    // 0..15 (K=128 per part)
#pragma unroll
      for (int ms = 0; ms < 4; ms++) {
        const int n = n0 + ms * 16 + l15;
        bf16x8 au = *(const bf16x8*)&W1L[(size_t)((kb << 8) + n) * 8];
        bf16x8 av = *(const bf16x8*)&W1L[(size_t)(4096 + (kb << 8) + n) * 8];
#pragma unroll
        for (int ni = 0; ni < 2; ni++) {
          aU[ms][ni] = MFMA16(au, bfr[ni][ks], aU[ms][ni]);
          aV[ms][ni] = MFMA16(av, bfr[ni][ks], aV[ms][ni]);
        }
      }
    }
    __syncthreads();                   // sync3: psum/fclip reads done, safe to overwrite
    // write-out: lane holds o = n0+ms*16+quad*4+r (r consecutive!), i = ni*16+l15
#pragma unroll
    for (int ms = 0; ms < 4; ms++) {
      const int ob = n0 + ms * 16 + quad * 4;
      const float4 bb = *(const float4*)&b1[ob];      // fold b1 into U'
      const int kb = ob >> 3, jo = ob & 7;            // jo in {0,4} -> 8B-aligned
#pragma unroll
      for (int ni = 0; ni < 2; ni++) {
        const int i = ni * 16 + l15;
        u32x2 uu, vv;
        uu[0] = pack2(f2bf(aU[ms][ni][0] + bb.x), f2bf(aU[ms][ni][1] + bb.y));
        uu[1] = pack2(f2bf(aU[ms][ni][2] + bb.z), f2bf(aU[ms][ni][3] + bb.w));
        vv[0] = pack2(f2bf(aV[ms][ni][0]), f2bf(aV[ms][ni][1]));
        vv[1] = pack2(f2bf(aV[ms][ni][2]), f2bf(aV[ms][ni][3]));
        *(u32x2*)&ULs[((kb << 5) + i) * 8 + jo] = uu;
        *(u32x2*)&VLs[((kb << 5) + i) * 8 + jo] = vv;
      }
    }
  }
  __syncthreads();                     // sync4: ULs/VLs ready; NO barriers after this

  // ------------- Main loop: e = relu(h @ W2^T + b2), barrier-free -------------
  // A = W2L (M = o), B = h in-register. W2L a-frags software-pipelined by 1 ks-iter.
  const int R0 = q * 256;
  const f32x4 zf = {0.f, 0.f, 0.f, 0.f};
  const short* Wp = W2L + (size_t)(n0 + l15) * 8;   // lane-invariant part folded
#pragma unroll 1
  for (int c = 0; c < 4; c++) {        // 4 chunks of 64 pair-rows
    f32x4 acc[4][4];                   // [ms=o-tile][ns=pair-tile]
#pragma unroll
    for (int ms = 0; ms < 4; ms++)
#pragma unroll
      for (int ns = 0; ns < 4; ns++) acc[ms][ns] = zf;
    const int i0 = q * 8 + c * 2;      // two i-values this chunk: i0, i0+1

    // prologue prefetch: ks=0 fragments (kb = quad)
    bf16x8 a0 = *(const bf16x8*)&Wp[((size_t)quad << 11)];
    bf16x8 a1 = *(const bf16x8*)&Wp[((size_t)quad << 11) + 16 * 8];
    bf16x8 a2 = *(const bf16x8*)&Wp[((size_t)quad << 11) + 32 * 8];
    bf16x8 a3 = *(const bf16x8*)&Wp[((size_t)quad << 11) + 48 * 8];

#pragma unroll 1
    for (int ks = 0; ks < 8; ks++) {
      // prefetch next iteration's fragments (wraps to ks=0 at chunk end — same
      // addresses the next chunk needs, so the pipeline stays primed across chunks)
      const size_t kbn = (size_t)((((ks + 1) & 7) * 4 + quad)) << 11;   // *256*8
      bf16x8 pa0 = *(const bf16x8*)&Wp[kbn];
      bf16x8 pa1 = *(const bf16x8*)&Wp[kbn + 16 * 8];
      bf16x8 pa2 = *(const bf16x8*)&Wp[kbn + 32 * 8];
      bf16x8 pa3 = *(const bf16x8*)&Wp[kbn + 48 * 8];

      const int kb = ks * 4 + quad;    // 0..31 (K=256)
      const bf16x8 u0 = *(const bf16x8*)&ULs[((kb << 5) + i0    ) * 8];  // quad-bcast
      const bf16x8 u1 = *(const bf16x8*)&ULs[((kb << 5) + i0 + 1) * 8];
      const bf16x8 v0 = *(const bf16x8*)&VLs[((kb << 5) + l15     ) * 8]; // 256B runs
      const bf16x8 v1 = *(const bf16x8*)&VLs[((kb << 5) + 16 + l15) * 8];
      {
        const bf16x8 hb = hfrag2(u0, v0);   // ns=0: pairs (i0, j=l15)
        acc[0][0] = MFMA16(a0, hb, acc[0][0]);
        acc[1][0] = MFMA16(a1, hb, acc[1][0]);
        acc[2][0] = MFMA16(a2, hb, acc[2][0]);
        acc[3][0] = MFMA16(a3, hb, acc[3][0]);
      }
      {
        const bf16x8 hb = hfrag2(u1, v0);   // ns=2: (i0+1, l15)
        acc[0][2] = MFMA16(a0, hb, acc[0][2]);
        acc[1][2] = MFMA16(a1, hb, acc[1][2]);
        acc[2][2] = MFMA16(a2, hb, acc[2][2]);
        acc[3][2] = MFMA16(a3, hb, acc[3][2]);
      }
      {
        const bf16x8 hb = hfrag2(u0, v1);   // ns=1: (i0, 16+l15)
        acc[0][1] = MFMA16(a0, hb, acc[0][1]);
        acc[1][1] = MFMA16(a1, hb, acc[1][1]);
        acc[2][1] = MFMA16(a2, hb, acc[2][1]);
        acc[3][1] = MFMA16(a3, hb, acc[3][1]);
      }
      {
        const bf16x8 hb = hfrag2(u1, v1);   // ns=3: (i0+1, 16+l15)
        acc[0][3] = MFMA16(a0, hb, acc[0][3]);
        acc[1][3] = MFMA16(a1, hb, acc[1][3]);
        acc[2][3] = MFMA16(a2, hb, acc[2][3]);
        acc[3][3] = MFMA16(a3, hb, acc[3][3]);
      }
      a0 = pa0; a1 = pa1; a2 = pa2; a3 = pa3;
    }

    // epilogue: bias + relu + f32x4 NT stores — FULLY unrolled (static acc indexing;
    // r6 lesson: runtime-ns loop sent acc to scratch, +280MB HBM traffic)
    const size_t prow = (size_t)bt * 1024 + R0 + c * 64;
#pragma unroll
    for (int ms = 0; ms < 4; ms++) {
      const int o = n0 + ms * 16 + quad * 4;
      const float4 bb = *(const float4*)&b2[o];
#pragma unroll
      for (int ns = 0; ns < 4; ns++) {
        float* po = out + (prow + ns * 16 + l15) * 256 + o;
        f32x4 r;
        r[0] = fmaxf(acc[ms][ns][0] + bb.x, 0.f);
        r[1] = fmaxf(acc[ms][ns][1] + bb.y, 0.f);
        r[2] = fmaxf(acc[ms][ns][2] + bb.z, 0.f);
        r[3] = fmaxf(acc[ms][ns][3] + bb.w, 0.f);
        __builtin_nontemporal_store(r, (f32x4*)po);
      }
    }
  }
}

extern "C" void kernel_launch(void* const* d_in, const int* in_sizes, int n_in,
                              void* d_out, int out_size, void* d_ws, size_t ws_size,
                              hipStream_t stream) {
  const float* objs = (const float*)d_in[0];
  const float* W1   = (const float*)d_in[1];
  const float* b1   = (const float*)d_in[2];
  const float* W2   = (const float*)d_in[3];
  const float* b2   = (const float*)d_in[4];
  float* out = (float*)d_out;
  short* W2L = (short*)d_ws;                 // 128 KB bf16 swizzled W2
  short* W1L = W2L + 8192 * 8;               // 128 KB bf16 swizzled W1 (U|V parts)

  prep_weights<<<64, 256, 0, stream>>>(W2, W1, W2L, W1L);
  orn_main<<<960, 256, 0, stream>>>(objs, b1, b2, W1L, W2L, out);
}

// Round 8
// 306.866 us; speedup vs baseline: 1.1834x; 1.0275x over previous
//
#include <hip/hip_runtime.h>

// ObjectRelationNetwork on MI355X — fp16 pipeline revision.
//
// Plateau analysis (r0/r5/r7 all ~315us total, orn ~150us): the invariant across
// all three structures is the h-build conversion tax: bf16 hfrag2 = ~80 VALU insts
// per 8 elems (shift/mask/add/max/f2bf/pack) -> 10k VALU insts/wave in the main
// loop; r6 profile showed VALUBusy 34.6% as the top pipe (MfmaUtil 9%, HBM 44%).
// This round: switch the whole MFMA path to fp16 (mfma_f32_16x16x32_f16, same
// fragment layout & rate). h = relu(u+v) becomes 4x v_pk_add_f16 + 4x v_pk_max_f16
// = 8 insts per 8 elems (10x VALU cut, dep depth 2). fp16 (10-bit mantissa) is
// MORE accurate than bf16 here (values small: |h|<8, weights ~0.05). All f32->f16
// converts are scalar RNE casts in cold paths (r2 lesson: no asm cvt tricks).
// Keeps: barrier-free main loop, W2L prefetch, NT f32x4 stores, 32KB LDS,
// launch_bounds(256,3).

typedef __attribute__((ext_vector_type(8))) _Float16 f16x8;  // 8 fp16 = 4 VGPRs
typedef __attribute__((ext_vector_type(4))) float f32x4;     // MFMA C/D, nt stores
typedef __attribute__((ext_vector_type(4))) unsigned u32x4;
typedef __attribute__((ext_vector_type(2))) unsigned u32x2;

#define MFMA16(a, b, c) __builtin_amdgcn_mfma_f32_16x16x32_f16((a), (b), (c), 0, 0, 0)
#define E_ELEMS 62914560ull   // 240*1024*256 e floats, then 245760 all_is_obj floats

__device__ __forceinline__ short f2h(float f) {   // RNE float->fp16 (v_cvt_f16_f32)
  _Float16 h = (_Float16)f;
  return __builtin_bit_cast(short, h);
}
__device__ __forceinline__ unsigned pack2(short lo, short hi) {
  return (unsigned)(unsigned short)lo | ((unsigned)(unsigned short)hi << 16);
}

// h-fragment: relu(u+v) on 8 fp16 — 4x v_pk_add_f16 + 4x v_pk_max_f16.
__device__ __forceinline__ f16x8 hfrag(f16x8 u, f16x8 v) {
  f16x8 h = u + v;
  const f16x8 z = __builtin_bit_cast(f16x8, (u32x4){0u, 0u, 0u, 0u});
  return __builtin_elementwise_max(h, z);
}

// ---- prep: W2 (256x256) -> W2L[kb=k>>3][n][k&7]  (K=256, fragment layout, fp16)
//            W1 (256x256) -> W1L[part][kb][n][jj]  (part 0: d 0..127 (U),
//                                                   part 1: d 128..255 (V))
__global__ void prep_weights(const float* __restrict__ W2, const float* __restrict__ W1,
                             short* __restrict__ W2L, short* __restrict__ W1L) {
  int t = blockIdx.x * 256 + threadIdx.x;   // 0..16383
  const float* src;
  short* dst;
  if (t < 8192) {
    int kb = t >> 8, n = t & 255;
    src = W2 + (size_t)n * 256 + kb * 8;
    dst = W2L + (size_t)t * 8;
  } else {
    int u = t - 8192;                       // 0..8191
    int part = u >> 12, kb = (u >> 8) & 15, n = u & 255;
    src = W1 + (size_t)n * 256 + part * 128 + kb * 8;
    dst = W1L + (size_t)u * 8;
  }
  float4 x = *(const float4*)src;
  float4 y = *(const float4*)(src + 4);
  short f[8];
  f[0] = f2h(x.x); f[1] = f2h(x.y); f[2] = f2h(x.z); f[3] = f2h(x.w);
  f[4] = f2h(y.x); f[5] = f2h(y.y); f[6] = f2h(y.z); f[7] = f2h(y.w);
  u32x4 o;
  o[0] = pack2(f[0], f[1]); o[1] = pack2(f[2], f[3]);
  o[2] = pack2(f[4], f[5]); o[3] = pack2(f[6], f[7]);
  *(u32x4*)dst = o;
}

// ---- main: 960 blocks (4 per (b,t)), 256 threads. LDS 32 KB; 3+ blocks/CU.
__global__ __launch_bounds__(256, 3) void orn_main(
    const float* __restrict__ objs, const float* __restrict__ b1,
    const float* __restrict__ b2, const short* __restrict__ W1L,
    const short* __restrict__ W2L, float* __restrict__ out) {
  __shared__ short ULs[32 * 32 * 8];   // [kb=o>>3][i][o&7]  fp16 of U' = O@W1a^T + b1
  __shared__ short VLs[32 * 32 * 8];   // [kb][j][jj]        fp16 of V  = O@W1b^T

  float* psum  = (float*)ULs;          // phase-1 scratch aliases (dead after sync3)
  float* fclip = (float*)VLs;

  const int tid = threadIdx.x;
  const int bid = blockIdx.x;
  const int bt  = bid >> 2;            // 0..239
  const int q   = bid & 3;             // row-quarter of this (b,t) slab
  const int b   = bt / 15;
  const int tm  = bt - b * 15;         // t-1
  const float* O = objs + (size_t)(b * 16 + tm + 1) * (32 * 128);

  const int lane = tid & 63;
  const int w    = tid >> 6;           // wave 0..3
  const int l15  = lane & 15;
  const int quad = lane >> 4;
  const int n0   = w * 64;             // this wave's o-col base (N split 4x64)

  // ---------------- Phase 1: fp32 row sums -> all_is_obj ----------------
  {
    int i = tid >> 3, c = tid & 7;
    const float* p = O + i * 128 + c * 16;
    float s = 0.f;
#pragma unroll
    for (int e = 0; e < 4; e++) {
      float4 v = *(const float4*)(p + e * 4);
      s += v.x + v.y + v.z + v.w;
    }
    psum[tid] = s;
  }
  __syncthreads();                     // sync1
  if (tid < 32) {
    float s = 0.f;
#pragma unroll
    for (int c = 0; c < 8; c++) s += psum[tid * 8 + c];
    fclip[tid] = fminf(fmaxf(s, 0.f), 1.f);
  }
  __syncthreads();                     // sync2
  {
    int p = q * 256 + tid;             // this WG's 256 pairs
    int i = p >> 5, j = p & 31;
    float v = fclip[i] * fclip[j] * (float)(tm + 1);
    out[E_ELEMS + (size_t)bt * 1024 + p] = fminf(fmaxf(v, 0.f), 1.f);
  }

  // ------- Phase 2: U',V (32 objs x 256 hidden) via MFMA, swapped operands -------
  // A = W1L (M = o rows), B = O (N = i cols).  D: row=quad*4+r -> o, col=l15 -> i.
  {
    // B-fragments from O: B[k = ks*32+quad*8+jj][i = ni*16+l15], fp16 RNE
    f16x8 bfr[2][4];
#pragma unroll
    for (int ni = 0; ni < 2; ni++)
#pragma unroll
      for (int ks = 0; ks < 4; ks++) {
        const float* p = O + (ni * 16 + l15) * 128 + ks * 32 + quad * 8;
        float4 x = *(const float4*)p;
        float4 y = *(const float4*)(p + 4);
        f16x8 f;
        f[0] = (_Float16)x.x; f[1] = (_Float16)x.y;
        f[2] = (_Float16)x.z; f[3] = (_Float16)x.w;
        f[4] = (_Float16)y.x; f[5] = (_Float16)y.y;
        f[6] = (_Float16)y.z; f[7] = (_Float16)y.w;
        bfr[ni][ks] = f;
      }
    const f32x4 zf = {0.f, 0.f, 0.f, 0.f};
    f32x4 aU[4][2], aV[4][2];
#pragma unroll
    for (int ms = 0; ms < 4; ms++)
#pragma unroll
      for (int ni = 0; ni < 2; ni++) { aU[ms][ni] = zf; aV[ms][ni] = zf; }
#pragma unroll
    for (int ks = 0; ks < 4; ks++) {
      const int kb = ks * 4 + quad;    // 0..15 (K=128 per part)
#pragma unroll
      for (int ms = 0; ms < 4; ms++) {
        const int n = n0 + ms * 16 + l15;
        f16x8 au = *(const f16x8*)&W1L[(size_t)((kb << 8) + n) * 8];
        f16x8 av = *(const f16x8*)&W1L[(size_t)(4096 + (kb << 8) + n) * 8];
#pragma unroll
        for (int ni = 0; ni < 2; ni++) {
          aU[ms][ni] = MFMA16(au, bfr[ni][ks], aU[ms][ni]);
          aV[ms][ni] = MFMA16(av, bfr[ni][ks], aV[ms][ni]);
        }
      }
    }
    __syncthreads();                   // sync3: psum/fclip reads done, safe to overwrite
    // write-out: lane holds o = n0+ms*16+quad*4+r (r consecutive!), i = ni*16+l15
#pragma unroll
    for (int ms = 0; ms < 4; ms++) {
      const int ob = n0 + ms * 16 + quad * 4;
      const float4 bb = *(const float4*)&b1[ob];      // fold b1 into U'
      const int kb = ob >> 3, jo = ob & 7;            // jo in {0,4} -> 8B-aligned
#pragma unroll
      for (int ni = 0; ni < 2; ni++) {
        const int i = ni * 16 + l15;
        u32x2 uu, vv;
        uu[0] = pack2(f2h(aU[ms][ni][0] + bb.x), f2h(aU[ms][ni][1] + bb.y));
        uu[1] = pack2(f2h(aU[ms][ni][2] + bb.z), f2h(aU[ms][ni][3] + bb.w));
        vv[0] = pack2(f2h(aV[ms][ni][0]), f2h(aV[ms][ni][1]));
        vv[1] = pack2(f2h(aV[ms][ni][2]), f2h(aV[ms][ni][3]));
        *(u32x2*)&ULs[((kb << 5) + i) * 8 + jo] = uu;
        *(u32x2*)&VLs[((kb << 5) + i) * 8 + jo] = vv;
      }
    }
  }
  __syncthreads();                     // sync4: ULs/VLs ready; NO barriers after this

  // ------------- Main loop: e = relu(h @ W2^T + b2), barrier-free -------------
  // A = W2L (M = o), B = h in-register (fp16 pk math). W2L prefetched 1 ks ahead.
  const int R0 = q * 256;
  const f32x4 zf = {0.f, 0.f, 0.f, 0.f};
  const short* Wp = W2L + (size_t)(n0 + l15) * 8;   // lane-invariant part folded
#pragma unroll 1
  for (int c = 0; c < 4; c++) {        // 4 chunks of 64 pair-rows
    f32x4 acc[4][4];                   // [ms=o-tile][ns=pair-tile]
#pragma unroll
    for (int ms = 0; ms < 4; ms++)
#pragma unroll
      for (int ns = 0; ns < 4; ns++) acc[ms][ns] = zf;
    const int i0 = q * 8 + c * 2;      // two i-values this chunk: i0, i0+1

    // prologue prefetch: ks=0 fragments (kb = quad)
    f16x8 a0 = *(const f16x8*)&Wp[((size_t)quad << 11)];
    f16x8 a1 = *(const f16x8*)&Wp[((size_t)quad << 11) + 16 * 8];
    f16x8 a2 = *(const f16x8*)&Wp[((size_t)quad << 11) + 32 * 8];
    f16x8 a3 = *(const f16x8*)&Wp[((size_t)quad << 11) + 48 * 8];

#pragma unroll 1
    for (int ks = 0; ks < 8; ks++) {
      // prefetch next iteration's fragments (wraps at chunk end: same addresses
      // the next chunk needs, keeps pipeline primed)
      const size_t kbn = (size_t)((((ks + 1) & 7) * 4 + quad)) << 11;   // *256*8
      f16x8 pa0 = *(const f16x8*)&Wp[kbn];
      f16x8 pa1 = *(const f16x8*)&Wp[kbn + 16 * 8];
      f16x8 pa2 = *(const f16x8*)&Wp[kbn + 32 * 8];
      f16x8 pa3 = *(const f16x8*)&Wp[kbn + 48 * 8];

      const int kb = ks * 4 + quad;    // 0..31 (K=256)
      const f16x8 u0 = *(const f16x8*)&ULs[((kb << 5) + i0    ) * 8];  // quad-bcast
      const f16x8 u1 = *(const f16x8*)&ULs[((kb << 5) + i0 + 1) * 8];
      const f16x8 v0 = *(const f16x8*)&VLs[((kb << 5) + l15     ) * 8]; // 256B runs
      const f16x8 v1 = *(const f16x8*)&VLs[((kb << 5) + 16 + l15) * 8];
      {
        const f16x8 hb = hfrag(u0, v0);     // ns=0: pairs (i0, j=l15)
        acc[0][0] = MFMA16(a0, hb, acc[0][0]);
        acc[1][0] = MFMA16(a1, hb, acc[1][0]);
        acc[2][0] = MFMA16(a2, hb, acc[2][0]);
        acc[3][0] = MFMA16(a3, hb, acc[3][0]);
      }
      {
        const f16x8 hb = hfrag(u1, v0);     // ns=2: (i0+1, l15)
        acc[0][2] = MFMA16(a0, hb, acc[0][2]);
        acc[1][2] = MFMA16(a1, hb, acc[1][2]);
        acc[2][2] = MFMA16(a2, hb, acc[2][2]);
        acc[3][2] = MFMA16(a3, hb, acc[3][2]);
      }
      {
        const f16x8 hb = hfrag(u0, v1);     // ns=1: (i0, 16+l15)
        acc[0][1] = MFMA16(a0, hb, acc[0][1]);
        acc[1][1] = MFMA16(a1, hb, acc[1][1]);
        acc[2][1] = MFMA16(a2, hb, acc[2][1]);
        acc[3][1] = MFMA16(a3, hb, acc[3][1]);
      }
      {
        const f16x8 hb = hfrag(u1, v1);     // ns=3: (i0+1, 16+l15)
        acc[0][3] = MFMA16(a0, hb, acc[0][3]);
        acc[1][3] = MFMA16(a1, hb, acc[1][3]);
        acc[2][3] = MFMA16(a2, hb, acc[2][3]);
        acc[3][3] = MFMA16(a3, hb, acc[3][3]);
      }
      a0 = pa0; a1 = pa1; a2 = pa2; a3 = pa3;
    }

    // epilogue: bias + relu + f32x4 NT stores — FULLY unrolled (static acc indexing;
    // r6 lesson: runtime index sent acc to scratch, +280MB HBM traffic)
    const size_t prow = (size_t)bt * 1024 + R0 + c * 64;
#pragma unroll
    for (int ms = 0; ms < 4; ms++) {
      const int o = n0 + ms * 16 + quad * 4;
      const float4 bb = *(const float4*)&b2[o];
#pragma unroll
      for (int ns = 0; ns < 4; ns++) {
        float* po = out + (prow + ns * 16 + l15) * 256 + o;
        f32x4 r;
        r[0] = fmaxf(acc[ms][ns][0] + bb.x, 0.f);
        r[1] = fmaxf(acc[ms][ns][1] + bb.y, 0.f);
        r[2] = fmaxf(acc[ms][ns][2] + bb.z, 0.f);
        r[3] = fmaxf(acc[ms][ns][3] + bb.w, 0.f);
        __builtin_nontemporal_store(r, (f32x4*)po);
      }
    }
  }
}

extern "C" void kernel_launch(void* const* d_in, const int* in_sizes, int n_in,
                              void* d_out, int out_size, void* d_ws, size_t ws_size,
                              hipStream_t stream) {
  const float* objs = (const float*)d_in[0];
  const float* W1   = (const float*)d_in[1];
  const float* b1   = (const float*)d_in[2];
  const float* W2   = (const float*)d_in[3];
  const float* b2   = (const float*)d_in[4];
  float* out = (float*)d_out;
  short* W2L = (short*)d_ws;                 // 128 KB fp16 swizzled W2
  short* W1L = W2L + 8192 * 8;               // 128 KB fp16 swizzled W1 (U|V parts)

  prep_weights<<<64, 256, 0, stream>>>(W2, W1, W2L, W1L);
  orn_main<<<960, 256, 0, stream>>>(objs, b1, b2, W1L, W2L, out);
}

// Round 9
// 284.009 us; speedup vs baseline: 1.2787x; 1.0805x over previous
//
#include <hip/hip_runtime.h>

// ObjectRelationNetwork on MI355X — fp16 pipeline + plain (L2-combining) stores.
//
// Budget model (r6 calibration): total = fill(~158) + prep(~2) + orn + theta(~47
// fixed harness overhead). orn_r8 ~= 100us vs ~55us ideal (40 store + 15 prologue).
// r8 lesson: fp16 pk-math h-build only -8us -> VALU exonerated. Unvaried lever:
// store mode. r8 wrote each 128B line as two 64B NT halves 4 insts apart; NT
// (no-allocate) defeats L2 write-combining -> partial-line HBM writes. This round:
// plain stores (same path as the 6.4TB/s fill), emitted row-major with the two
// half-line stores back-to-back. Watch FETCH_SIZE for W2L eviction churn.
// Keeps: fp16 MFMA path, barrier-free main loop, W2L prefetch, 32KB LDS, (256,3).

typedef __attribute__((ext_vector_type(8))) _Float16 f16x8;  // 8 fp16 = 4 VGPRs
typedef __attribute__((ext_vector_type(4))) float f32x4;     // MFMA C/D, stores
typedef __attribute__((ext_vector_type(4))) unsigned u32x4;
typedef __attribute__((ext_vector_type(2))) unsigned u32x2;

#define MFMA16(a, b, c) __builtin_amdgcn_mfma_f32_16x16x32_f16((a), (b), (c), 0, 0, 0)
#define E_ELEMS 62914560ull   // 240*1024*256 e floats, then 245760 all_is_obj floats

__device__ __forceinline__ short f2h(float f) {   // RNE float->fp16 (v_cvt_f16_f32)
  _Float16 h = (_Float16)f;
  return __builtin_bit_cast(short, h);
}
__device__ __forceinline__ unsigned pack2(short lo, short hi) {
  return (unsigned)(unsigned short)lo | ((unsigned)(unsigned short)hi << 16);
}

// h-fragment: relu(u+v) on 8 fp16 — 4x v_pk_add_f16 + 4x v_pk_max_f16.
__device__ __forceinline__ f16x8 hfrag(f16x8 u, f16x8 v) {
  f16x8 h = u + v;
  const f16x8 z = __builtin_bit_cast(f16x8, (u32x4){0u, 0u, 0u, 0u});
  return __builtin_elementwise_max(h, z);
}

// ---- prep: W2 (256x256) -> W2L[kb=k>>3][n][k&7]  (K=256, fragment layout, fp16)
//            W1 (256x256) -> W1L[part][kb][n][jj]  (part 0: d 0..127 (U),
//                                                   part 1: d 128..255 (V))
__global__ void prep_weights(const float* __restrict__ W2, const float* __restrict__ W1,
                             short* __restrict__ W2L, short* __restrict__ W1L) {
  int t = blockIdx.x * 256 + threadIdx.x;   // 0..16383
  const float* src;
  short* dst;
  if (t < 8192) {
    int kb = t >> 8, n = t & 255;
    src = W2 + (size_t)n * 256 + kb * 8;
    dst = W2L + (size_t)t * 8;
  } else {
    int u = t - 8192;                       // 0..8191
    int part = u >> 12, kb = (u >> 8) & 15, n = u & 255;
    src = W1 + (size_t)n * 256 + part * 128 + kb * 8;
    dst = W1L + (size_t)u * 8;
  }
  float4 x = *(const float4*)src;
  float4 y = *(const float4*)(src + 4);
  short f[8];
  f[0] = f2h(x.x); f[1] = f2h(x.y); f[2] = f2h(x.z); f[3] = f2h(x.w);
  f[4] = f2h(y.x); f[5] = f2h(y.y); f[6] = f2h(y.z); f[7] = f2h(y.w);
  u32x4 o;
  o[0] = pack2(f[0], f[1]); o[1] = pack2(f[2], f[3]);
  o[2] = pack2(f[4], f[5]); o[3] = pack2(f[6], f[7]);
  *(u32x4*)dst = o;
}

// ---- main: 960 blocks (4 per (b,t)), 256 threads. LDS 32 KB; 3 blocks/CU.
__global__ __launch_bounds__(256, 3) void orn_main(
    const float* __restrict__ objs, const float* __restrict__ b1,
    const float* __restrict__ b2, const short* __restrict__ W1L,
    const short* __restrict__ W2L, float* __restrict__ out) {
  __shared__ short ULs[32 * 32 * 8];   // [kb=o>>3][i][o&7]  fp16 of U' = O@W1a^T + b1
  __shared__ short VLs[32 * 32 * 8];   // [kb][j][jj]        fp16 of V  = O@W1b^T

  float* psum  = (float*)ULs;          // phase-1 scratch aliases (dead after sync3)
  float* fclip = (float*)VLs;

  const int tid = threadIdx.x;
  const int bid = blockIdx.x;
  const int bt  = bid >> 2;            // 0..239
  const int q   = bid & 3;             // row-quarter of this (b,t) slab
  const int b   = bt / 15;
  const int tm  = bt - b * 15;         // t-1
  const float* O = objs + (size_t)(b * 16 + tm + 1) * (32 * 128);

  const int lane = tid & 63;
  const int w    = tid >> 6;           // wave 0..3
  const int l15  = lane & 15;
  const int quad = lane >> 4;
  const int n0   = w * 64;             // this wave's o-col base (N split 4x64)

  // ---------------- Phase 1: fp32 row sums -> all_is_obj ----------------
  {
    int i = tid >> 3, c = tid & 7;
    const float* p = O + i * 128 + c * 16;
    float s = 0.f;
#pragma unroll
    for (int e = 0; e < 4; e++) {
      float4 v = *(const float4*)(p + e * 4);
      s += v.x + v.y + v.z + v.w;
    }
    psum[tid] = s;
  }
  __syncthreads();                     // sync1
  if (tid < 32) {
    float s = 0.f;
#pragma unroll
    for (int c = 0; c < 8; c++) s += psum[tid * 8 + c];
    fclip[tid] = fminf(fmaxf(s, 0.f), 1.f);
  }
  __syncthreads();                     // sync2
  {
    int p = q * 256 + tid;             // this WG's 256 pairs
    int i = p >> 5, j = p & 31;
    float v = fclip[i] * fclip[j] * (float)(tm + 1);
    out[E_ELEMS + (size_t)bt * 1024 + p] = fminf(fmaxf(v, 0.f), 1.f);
  }

  // ------- Phase 2: U',V (32 objs x 256 hidden) via MFMA, swapped operands -------
  // A = W1L (M = o rows), B = O (N = i cols).  D: row=quad*4+r -> o, col=l15 -> i.
  {
    // B-fragments from O: B[k = ks*32+quad*8+jj][i = ni*16+l15], fp16 RNE
    f16x8 bfr[2][4];
#pragma unroll
    for (int ni = 0; ni < 2; ni++)
#pragma unroll
      for (int ks = 0; ks < 4; ks++) {
        const float* p = O + (ni * 16 + l15) * 128 + ks * 32 + quad * 8;
        float4 x = *(const float4*)p;
        float4 y = *(const float4*)(p + 4);
        f16x8 f;
        f[0] = (_Float16)x.x; f[1] = (_Float16)x.y;
        f[2] = (_Float16)x.z; f[3] = (_Float16)x.w;
        f[4] = (_Float16)y.x; f[5] = (_Float16)y.y;
        f[6] = (_Float16)y.z; f[7] = (_Float16)y.w;
        bfr[ni][ks] = f;
      }
    const f32x4 zf = {0.f, 0.f, 0.f, 0.f};
    f32x4 aU[4][2], aV[4][2];
#pragma unroll
    for (int ms = 0; ms < 4; ms++)
#pragma unroll
      for (int ni = 0; ni < 2; ni++) { aU[ms][ni] = zf; aV[ms][ni] = zf; }
#pragma unroll
    for (int ks = 0; ks < 4; ks++) {
      const int kb = ks * 4 + quad;    // 0..15 (K=128 per part)
#pragma unroll
      for (int ms = 0; ms < 4; ms++) {
        const int n = n0 + ms * 16 + l15;
        f16x8 au = *(const f16x8*)&W1L[(size_t)((kb << 8) + n) * 8];
        f16x8 av = *(const f16x8*)&W1L[(size_t)(4096 + (kb << 8) + n) * 8];
#pragma unroll
        for (int ni = 0; ni < 2; ni++) {
          aU[ms][ni] = MFMA16(au, bfr[ni][ks], aU[ms][ni]);
          aV[ms][ni] = MFMA16(av, bfr[ni][ks], aV[ms][ni]);
        }
      }
    }
    __syncthreads();                   // sync3: psum/fclip reads done, safe to overwrite
    // write-out: lane holds o = n0+ms*16+quad*4+r (r consecutive!), i = ni*16+l15
#pragma unroll
    for (int ms = 0; ms < 4; ms++) {
      const int ob = n0 + ms * 16 + quad * 4;
      const float4 bb = *(const float4*)&b1[ob];      // fold b1 into U'
      const int kb = ob >> 3, jo = ob & 7;            // jo in {0,4} -> 8B-aligned
#pragma unroll
      for (int ni = 0; ni < 2; ni++) {
        const int i = ni * 16 + l15;
        u32x2 uu, vv;
        uu[0] = pack2(f2h(aU[ms][ni][0] + bb.x), f2h(aU[ms][ni][1] + bb.y));
        uu[1] = pack2(f2h(aU[ms][ni][2] + bb.z), f2h(aU[ms][ni][3] + bb.w));
        vv[0] = pack2(f2h(aV[ms][ni][0]), f2h(aV[ms][ni][1]));
        vv[1] = pack2(f2h(aV[ms][ni][2]), f2h(aV[ms][ni][3]));
        *(u32x2*)&ULs[((kb << 5) + i) * 8 + jo] = uu;
        *(u32x2*)&VLs[((kb << 5) + i) * 8 + jo] = vv;
      }
    }
  }
  __syncthreads();                     // sync4: ULs/VLs ready; NO barriers after this

  // ------------- Main loop: e = relu(h @ W2^T + b2), barrier-free -------------
  // A = W2L (M = o), B = h in-register (fp16 pk math). W2L prefetched 1 ks ahead.
  const int R0 = q * 256;
  const f32x4 zf = {0.f, 0.f, 0.f, 0.f};
  const short* Wp = W2L + (size_t)(n0 + l15) * 8;   // lane-invariant part folded
#pragma unroll 1
  for (int c = 0; c < 4; c++) {        // 4 chunks of 64 pair-rows
    f32x4 acc[4][4];                   // [ms=o-tile][ns=pair-tile]
#pragma unroll
    for (int ms = 0; ms < 4; ms++)
#pragma unroll
      for (int ns = 0; ns < 4; ns++) acc[ms][ns] = zf;
    const int i0 = q * 8 + c * 2;      // two i-values this chunk: i0, i0+1

    // prologue prefetch: ks=0 fragments (kb = quad)
    f16x8 a0 = *(const f16x8*)&Wp[((size_t)quad << 11)];
    f16x8 a1 = *(const f16x8*)&Wp[((size_t)quad << 11) + 16 * 8];
    f16x8 a2 = *(const f16x8*)&Wp[((size_t)quad << 11) + 32 * 8];
    f16x8 a3 = *(const f16x8*)&Wp[((size_t)quad << 11) + 48 * 8];

#pragma unroll 1
    for (int ks = 0; ks < 8; ks++) {
      // prefetch next iteration's fragments (wraps at chunk end: same addresses
      // the next chunk needs, keeps pipeline primed)
      const size_t kbn = (size_t)((((ks + 1) & 7) * 4 + quad)) << 11;   // *256*8
      f16x8 pa0 = *(const f16x8*)&Wp[kbn];
      f16x8 pa1 = *(const f16x8*)&Wp[kbn + 16 * 8];
      f16x8 pa2 = *(const f16x8*)&Wp[kbn + 32 * 8];
      f16x8 pa3 = *(const f16x8*)&Wp[kbn + 48 * 8];

      const int kb = ks * 4 + quad;    // 0..31 (K=256)
      const f16x8 u0 = *(const f16x8*)&ULs[((kb << 5) + i0    ) * 8];  // quad-bcast
      const f16x8 u1 = *(const f16x8*)&ULs[((kb << 5) + i0 + 1) * 8];
      const f16x8 v0 = *(const f16x8*)&VLs[((kb << 5) + l15     ) * 8]; // 256B runs
      const f16x8 v1 = *(const f16x8*)&VLs[((kb << 5) + 16 + l15) * 8];
      {
        const f16x8 hb = hfrag(u0, v0);     // ns=0: pairs (i0, j=l15)
        acc[0][0] = MFMA16(a0, hb, acc[0][0]);
        acc[1][0] = MFMA16(a1, hb, acc[1][0]);
        acc[2][0] = MFMA16(a2, hb, acc[2][0]);
        acc[3][0] = MFMA16(a3, hb, acc[3][0]);
      }
      {
        const f16x8 hb = hfrag(u1, v0);     // ns=2: (i0+1, l15)
        acc[0][2] = MFMA16(a0, hb, acc[0][2]);
        acc[1][2] = MFMA16(a1, hb, acc[1][2]);
        acc[2][2] = MFMA16(a2, hb, acc[2][2]);
        acc[3][2] = MFMA16(a3, hb, acc[3][2]);
      }
      {
        const f16x8 hb = hfrag(u0, v1);     // ns=1: (i0, 16+l15)
        acc[0][1] = MFMA16(a0, hb, acc[0][1]);
        acc[1][1] = MFMA16(a1, hb, acc[1][1]);
        acc[2][1] = MFMA16(a2, hb, acc[2][1]);
        acc[3][1] = MFMA16(a3, hb, acc[3][1]);
      }
      {
        const f16x8 hb = hfrag(u1, v1);     // ns=3: (i0+1, 16+l15)
        acc[0][3] = MFMA16(a0, hb, acc[0][3]);
        acc[1][3] = MFMA16(a1, hb, acc[1][3]);
        acc[2][3] = MFMA16(a2, hb, acc[2][3]);
        acc[3][3] = MFMA16(a3, hb, acc[3][3]);
      }
      a0 = pa0; a1 = pa1; a2 = pa2; a3 = pa3;
    }

    // epilogue: bias + relu + PLAIN f32x4 stores, row-major emission so the two
    // 64B halves of each 128B line (ms pairs) are back-to-back -> L2 combines to
    // full-line evictions. (r8 and earlier: NT half-line writes, 64B apart in
    // program order interleaved across rows.) Static acc indexing throughout.
    const size_t prow = (size_t)bt * 1024 + R0 + c * 64;
    const float4 bb0 = *(const float4*)&b2[n0 +  0 + quad * 4];
    const float4 bb1 = *(const float4*)&b2[n0 + 16 + quad * 4];
    const float4 bb2 = *(const float4*)&b2[n0 + 32 + quad * 4];
    const float4 bb3 = *(const float4*)&b2[n0 + 48 + quad * 4];
#pragma unroll
    for (int ns = 0; ns < 4; ns++) {
      float* rp = out + (prow + ns * 16 + l15) * 256 + n0 + quad * 4;
      f32x4 r;
      r[0] = fmaxf(acc[0][ns][0] + bb0.x, 0.f);
      r[1] = fmaxf(acc[0][ns][1] + bb0.y, 0.f);
      r[2] = fmaxf(acc[0][ns][2] + bb0.z, 0.f);
      r[3] = fmaxf(acc[0][ns][3] + bb0.w, 0.f);
      *(f32x4*)(rp + 0)  = r;
      r[0] = fmaxf(acc[1][ns][0] + bb1.x, 0.f);
      r[1] = fmaxf(acc[1][ns][1] + bb1.y, 0.f);
      r[2] = fmaxf(acc[1][ns][2] + bb1.z, 0.f);
      r[3] = fmaxf(acc[1][ns][3] + bb1.w, 0.f);
      *(f32x4*)(rp + 16) = r;
      r[0] = fmaxf(acc[2][ns][0] + bb2.x, 0.f);
      r[1] = fmaxf(acc[2][ns][1] + bb2.y, 0.f);
      r[2] = fmaxf(acc[2][ns][2] + bb2.z, 0.f);
      r[3] = fmaxf(acc[2][ns][3] + bb2.w, 0.f);
      *(f32x4*)(rp + 32) = r;
      r[0] = fmaxf(acc[3][ns][0] + bb3.x, 0.f);
      r[1] = fmaxf(acc[3][ns][1] + bb3.y, 0.f);
      r[2] = fmaxf(acc[3][ns][2] + bb3.z, 0.f);
      r[3] = fmaxf(acc[3][ns][3] + bb3.w, 0.f);
      *(f32x4*)(rp + 48) = r;
    }
  }
}

extern "C" void kernel_launch(void* const* d_in, const int* in_sizes, int n_in,
                              void* d_out, int out_size, void* d_ws, size_t ws_size,
                              hipStream_t stream) {
  const float* objs = (const float*)d_in[0];
  const float* W1   = (const float*)d_in[1];
  const float* b1   = (const float*)d_in[2];
  const float* W2   = (const float*)d_in[3];
  const float* b2   = (const float*)d_in[4];
  float* out = (float*)d_out;
  short* W2L = (short*)d_ws;                 // 128 KB fp16 swizzled W2
  short* W1L = W2L + 8192 * 8;               // 128 KB fp16 swizzled W1 (U|V parts)

  prep_weights<<<64, 256, 0, stream>>>(W2, W1, W2L, W1L);
  orn_main<<<960, 256, 0, stream>>>(objs, b1, b2, W1L, W2L, out);
}

// Round 10
// 279.276 us; speedup vs baseline: 1.3004x; 1.0170x over previous
//
#include <hip/hip_runtime.h>

// ObjectRelationNetwork on MI355X — fp16 pipeline, plain stores, full residency.
//
// Budget (r9): total 284 = fill ~152 + prep ~2 + theta ~47 + orn ~83. orn floor
// ~55 (38us store-bound + prologue). Gap theory: 960 blocks @ 3/CU = 768 slots ->
// 1.25 dispatch rounds; 192 stragglers at 1/4 occupancy stretch the kernel ~1.25x.
// This round: __launch_bounds__(256,4) -> 1024 slots, ALL 960 blocks co-resident.
// VGPR must stay <=128: the W2L prefetch (r7: proven null vs r5) is deleted,
// freeing 16 VGPRs -> in-loop live ~110 (r6 measured 84 for this structure).
// Keeps (all verified): fp16 MFMA path (r8), barrier-free main loop (r5), plain
// back-to-back full-line stores (r9, -23us), RNE converts only (r2 lesson),
// static acc indexing (r6 lesson).

typedef __attribute__((ext_vector_type(8))) _Float16 f16x8;  // 8 fp16 = 4 VGPRs
typedef __attribute__((ext_vector_type(4))) float f32x4;     // MFMA C/D, stores
typedef __attribute__((ext_vector_type(4))) unsigned u32x4;
typedef __attribute__((ext_vector_type(2))) unsigned u32x2;

#define MFMA16(a, b, c) __builtin_amdgcn_mfma_f32_16x16x32_f16((a), (b), (c), 0, 0, 0)
#define E_ELEMS 62914560ull   // 240*1024*256 e floats, then 245760 all_is_obj floats

__device__ __forceinline__ short f2h(float f) {   // RNE float->fp16 (v_cvt_f16_f32)
  _Float16 h = (_Float16)f;
  return __builtin_bit_cast(short, h);
}
__device__ __forceinline__ unsigned pack2(short lo, short hi) {
  return (unsigned)(unsigned short)lo | ((unsigned)(unsigned short)hi << 16);
}

// h-fragment: relu(u+v) on 8 fp16 — 4x v_pk_add_f16 + 4x v_pk_max_f16.
__device__ __forceinline__ f16x8 hfrag(f16x8 u, f16x8 v) {
  f16x8 h = u + v;
  const f16x8 z = __builtin_bit_cast(f16x8, (u32x4){0u, 0u, 0u, 0u});
  return __builtin_elementwise_max(h, z);
}

// ---- prep: W2 (256x256) -> W2L[kb=k>>3][n][k&7]  (K=256, fragment layout, fp16)
//            W1 (256x256) -> W1L[part][kb][n][jj]  (part 0: d 0..127 (U),
//                                                   part 1: d 128..255 (V))
__global__ void prep_weights(const float* __restrict__ W2, const float* __restrict__ W1,
                             short* __restrict__ W2L, short* __restrict__ W1L) {
  int t = blockIdx.x * 256 + threadIdx.x;   // 0..16383
  const float* src;
  short* dst;
  if (t < 8192) {
    int kb = t >> 8, n = t & 255;
    src = W2 + (size_t)n * 256 + kb * 8;
    dst = W2L + (size_t)t * 8;
  } else {
    int u = t - 8192;                       // 0..8191
    int part = u >> 12, kb = (u >> 8) & 15, n = u & 255;
    src = W1 + (size_t)n * 256 + part * 128 + kb * 8;
    dst = W1L + (size_t)u * 8;
  }
  float4 x = *(const float4*)src;
  float4 y = *(const float4*)(src + 4);
  short f[8];
  f[0] = f2h(x.x); f[1] = f2h(x.y); f[2] = f2h(x.z); f[3] = f2h(x.w);
  f[4] = f2h(y.x); f[5] = f2h(y.y); f[6] = f2h(y.z); f[7] = f2h(y.w);
  u32x4 o;
  o[0] = pack2(f[0], f[1]); o[1] = pack2(f[2], f[3]);
  o[2] = pack2(f[4], f[5]); o[3] = pack2(f[6], f[7]);
  *(u32x4*)dst = o;
}

// ---- main: 960 blocks (4 per (b,t)), 256 threads. LDS 32 KB; 4 blocks/CU.
__global__ __launch_bounds__(256, 4) void orn_main(
    const float* __restrict__ objs, const float* __restrict__ b1,
    const float* __restrict__ b2, const short* __restrict__ W1L,
    const short* __restrict__ W2L, float* __restrict__ out) {
  __shared__ short ULs[32 * 32 * 8];   // [kb=o>>3][i][o&7]  fp16 of U' = O@W1a^T + b1
  __shared__ short VLs[32 * 32 * 8];   // [kb][j][jj]        fp16 of V  = O@W1b^T

  float* psum  = (float*)ULs;          // phase-1 scratch aliases (dead after sync3)
  float* fclip = (float*)VLs;

  const int tid = threadIdx.x;
  const int bid = blockIdx.x;
  const int bt  = bid >> 2;            // 0..239
  const int q   = bid & 3;             // row-quarter of this (b,t) slab
  const int b   = bt / 15;
  const int tm  = bt - b * 15;         // t-1
  const float* O = objs + (size_t)(b * 16 + tm + 1) * (32 * 128);

  const int lane = tid & 63;
  const int w    = tid >> 6;           // wave 0..3
  const int l15  = lane & 15;
  const int quad = lane >> 4;
  const int n0   = w * 64;             // this wave's o-col base (N split 4x64)

  // ---------------- Phase 1: fp32 row sums -> all_is_obj ----------------
  {
    int i = tid >> 3, c = tid & 7;
    const float* p = O + i * 128 + c * 16;
    float s = 0.f;
#pragma unroll
    for (int e = 0; e < 4; e++) {
      float4 v = *(const float4*)(p + e * 4);
      s += v.x + v.y + v.z + v.w;
    }
    psum[tid] = s;
  }
  __syncthreads();                     // sync1
  if (tid < 32) {
    float s = 0.f;
#pragma unroll
    for (int c = 0; c < 8; c++) s += psum[tid * 8 + c];
    fclip[tid] = fminf(fmaxf(s, 0.f), 1.f);
  }
  __syncthreads();                     // sync2
  {
    int p = q * 256 + tid;             // this WG's 256 pairs
    int i = p >> 5, j = p & 31;
    float v = fclip[i] * fclip[j] * (float)(tm + 1);
    out[E_ELEMS + (size_t)bt * 1024 + p] = fminf(fmaxf(v, 0.f), 1.f);
  }

  // ------- Phase 2: U',V (32 objs x 256 hidden) via MFMA, swapped operands -------
  // A = W1L (M = o rows), B = O (N = i cols).  D: row=quad*4+r -> o, col=l15 -> i.
  {
    // B-fragments from O: B[k = ks*32+quad*8+jj][i = ni*16+l15], fp16 RNE
    f16x8 bfr[2][4];
#pragma unroll
    for (int ni = 0; ni < 2; ni++)
#pragma unroll
      for (int ks = 0; ks < 4; ks++) {
        const float* p = O + (ni * 16 + l15) * 128 + ks * 32 + quad * 8;
        float4 x = *(const float4*)p;
        float4 y = *(const float4*)(p + 4);
        f16x8 f;
        f[0] = (_Float16)x.x; f[1] = (_Float16)x.y;
        f[2] = (_Float16)x.z; f[3] = (_Float16)x.w;
        f[4] = (_Float16)y.x; f[5] = (_Float16)y.y;
        f[6] = (_Float16)y.z; f[7] = (_Float16)y.w;
        bfr[ni][ks] = f;
      }
    const f32x4 zf = {0.f, 0.f, 0.f, 0.f};
    f32x4 aU[4][2], aV[4][2];
#pragma unroll
    for (int ms = 0; ms < 4; ms++)
#pragma unroll
      for (int ni = 0; ni < 2; ni++) { aU[ms][ni] = zf; aV[ms][ni] = zf; }
#pragma unroll
    for (int ks = 0; ks < 4; ks++) {
      const int kb = ks * 4 + quad;    // 0..15 (K=128 per part)
#pragma unroll
      for (int ms = 0; ms < 4; ms++) {
        const int n = n0 + ms * 16 + l15;
        f16x8 au = *(const f16x8*)&W1L[(size_t)((kb << 8) + n) * 8];
        f16x8 av = *(const f16x8*)&W1L[(size_t)(4096 + (kb << 8) + n) * 8];
#pragma unroll
        for (int ni = 0; ni < 2; ni++) {
          aU[ms][ni] = MFMA16(au, bfr[ni][ks], aU[ms][ni]);
          aV[ms][ni] = MFMA16(av, bfr[ni][ks], aV[ms][ni]);
        }
      }
    }
    __syncthreads();                   // sync3: psum/fclip reads done, safe to overwrite
    // write-out: lane holds o = n0+ms*16+quad*4+r (r consecutive!), i = ni*16+l15
#pragma unroll
    for (int ms = 0; ms < 4; ms++) {
      const int ob = n0 + ms * 16 + quad * 4;
      const float4 bb = *(const float4*)&b1[ob];      // fold b1 into U'
      const int kb = ob >> 3, jo = ob & 7;            // jo in {0,4} -> 8B-aligned
#pragma unroll
      for (int ni = 0; ni < 2; ni++) {
        const int i = ni * 16 + l15;
        u32x2 uu, vv;
        uu[0] = pack2(f2h(aU[ms][ni][0] + bb.x), f2h(aU[ms][ni][1] + bb.y));
        uu[1] = pack2(f2h(aU[ms][ni][2] + bb.z), f2h(aU[ms][ni][3] + bb.w));
        vv[0] = pack2(f2h(aV[ms][ni][0]), f2h(aV[ms][ni][1]));
        vv[1] = pack2(f2h(aV[ms][ni][2]), f2h(aV[ms][ni][3]));
        *(u32x2*)&ULs[((kb << 5) + i) * 8 + jo] = uu;
        *(u32x2*)&VLs[((kb << 5) + i) * 8 + jo] = vv;
      }
    }
  }
  __syncthreads();                     // sync4: ULs/VLs ready; NO barriers after this

  // ------------- Main loop: e = relu(h @ W2^T + b2), barrier-free -------------
  // A = W2L (M = o), B = h in-register (fp16 pk math). No prefetch (r7: null lever;
  // deleting it frees 16 VGPRs for the 128 cap at 4 blocks/CU).
  const int R0 = q * 256;
  const f32x4 zf = {0.f, 0.f, 0.f, 0.f};
  const short* Wp = W2L + (size_t)(n0 + l15) * 8;   // lane-invariant part folded
#pragma unroll 1
  for (int c = 0; c < 4; c++) {        // 4 chunks of 64 pair-rows
    f32x4 acc[4][4];                   // [ms=o-tile][ns=pair-tile]
#pragma unroll
    for (int ms = 0; ms < 4; ms++)
#pragma unroll
      for (int ns = 0; ns < 4; ns++) acc[ms][ns] = zf;
    const int i0 = q * 8 + c * 2;      // two i-values this chunk: i0, i0+1

#pragma unroll 1
    for (int ks = 0; ks < 8; ks++) {
      const int kb = ks * 4 + quad;    // 0..31 (K=256)
      const size_t kbb = (size_t)kb << 11;            // *256*8 shorts
      const f16x8 a0 = *(const f16x8*)&Wp[kbb];
      const f16x8 a1 = *(const f16x8*)&Wp[kbb + 16 * 8];
      const f16x8 a2 = *(const f16x8*)&Wp[kbb + 32 * 8];
      const f16x8 a3 = *(const f16x8*)&Wp[kbb + 48 * 8];
      const f16x8 u0 = *(const f16x8*)&ULs[((kb << 5) + i0    ) * 8];  // quad-bcast
      const f16x8 u1 = *(const f16x8*)&ULs[((kb << 5) + i0 + 1) * 8];
      const f16x8 v0 = *(const f16x8*)&VLs[((kb << 5) + l15     ) * 8]; // 256B runs
      const f16x8 v1 = *(const f16x8*)&VLs[((kb << 5) + 16 + l15) * 8];
      {
        const f16x8 hb = hfrag(u0, v0);     // ns=0: pairs (i0, j=l15)
        acc[0][0] = MFMA16(a0, hb, acc[0][0]);
        acc[1][0] = MFMA16(a1, hb, acc[1][0]);
        acc[2][0] = MFMA16(a2, hb, acc[2][0]);
        acc[3][0] = MFMA16(a3, hb, acc[3][0]);
      }
      {
        const f16x8 hb = hfrag(u1, v0);     // ns=2: (i0+1, l15)
        acc[0][2] = MFMA16(a0, hb, acc[0][2]);
        acc[1][2] = MFMA16(a1, hb, acc[1][2]);
        acc[2][2] = MFMA16(a2, hb, acc[2][2]);
        acc[3][2] = MFMA16(a3, hb, acc[3][2]);
      }
      {
        const f16x8 hb = hfrag(u0, v1);     // ns=1: (i0, 16+l15)
        acc[0][1] = MFMA16(a0, hb, acc[0][1]);
        acc[1][1] = MFMA16(a1, hb, acc[1][1]);
        acc[2][1] = MFMA16(a2, hb, acc[2][1]);
        acc[3][1] = MFMA16(a3, hb, acc[3][1]);
      }
      {
        const f16x8 hb = hfrag(u1, v1);     // ns=3: (i0+1, 16+l15)
        acc[0][3] = MFMA16(a0, hb, acc[0][3]);
        acc[1][3] = MFMA16(a1, hb, acc[1][3]);
        acc[2][3] = MFMA16(a2, hb, acc[2][3]);
        acc[3][3] = MFMA16(a3, hb, acc[3][3]);
      }
    }

    // epilogue: bias + relu + PLAIN f32x4 stores, row-major emission so the two
    // 64B halves of each 128B line are back-to-back -> L2 combines to full-line
    // evictions (r9: -23us vs NT interleaved). Static acc indexing (r6 lesson).
    const size_t prow = (size_t)bt * 1024 + R0 + c * 64;
    const float4 bb0 = *(const float4*)&b2[n0 +  0 + quad * 4];
    const float4 bb1 = *(const float4*)&b2[n0 + 16 + quad * 4];
    const float4 bb2 = *(const float4*)&b2[n0 + 32 + quad * 4];
    const float4 bb3 = *(const float4*)&b2[n0 + 48 + quad * 4];
#pragma unroll
    for (int ns = 0; ns < 4; ns++) {
      float* rp = out + (prow + ns * 16 + l15) * 256 + n0 + quad * 4;
      f32x4 r;
      r[0] = fmaxf(acc[0][ns][0] + bb0.x, 0.f);
      r[1] = fmaxf(acc[0][ns][1] + bb0.y, 0.f);
      r[2] = fmaxf(acc[0][ns][2] + bb0.z, 0.f);
      r[3] = fmaxf(acc[0][ns][3] + bb0.w, 0.f);
      *(f32x4*)(rp + 0)  = r;
      r[0] = fmaxf(acc[1][ns][0] + bb1.x, 0.f);
      r[1] = fmaxf(acc[1][ns][1] + bb1.y, 0.f);
      r[2] = fmaxf(acc[1][ns][2] + bb1.z, 0.f);
      r[3] = fmaxf(acc[1][ns][3] + bb1.w, 0.f);
      *(f32x4*)(rp + 16) = r;
      r[0] = fmaxf(acc[2][ns][0] + bb2.x, 0.f);
      r[1] = fmaxf(acc[2][ns][1] + bb2.y, 0.f);
      r[2] = fmaxf(acc[2][ns][2] + bb2.z, 0.f);
      r[3] = fmaxf(acc[2][ns][3] + bb2.w, 0.f);
      *(f32x4*)(rp + 32) = r;
      r[0] = fmaxf(acc[3][ns][0] + bb3.x, 0.f);
      r[1] = fmaxf(acc[3][ns][1] + bb3.y, 0.f);
      r[2] = fmaxf(acc[3][ns][2] + bb3.z, 0.f);
      r[3] = fmaxf(acc[3][ns][3] + bb3.w, 0.f);
      *(f32x4*)(rp + 48) = r;
    }
  }
}

extern "C" void kernel_launch(void* const* d_in, const int* in_sizes, int n_in,
                              void* d_out, int out_size, void* d_ws, size_t ws_size,
                              hipStream_t stream) {
  const float* objs = (const float*)d_in[0];
  const float* W1   = (const float*)d_in[1];
  const float* b1   = (const float*)d_in[2];
  const float* W2   = (const float*)d_in[3];
  const float* b2   = (const float*)d_in[4];
  float* out = (float*)d_out;
  short* W2L = (short*)d_ws;                 // 128 KB fp16 swizzled W2
  short* W1L = W2L + 8192 * 8;               // 128 KB fp16 swizzled W1 (U|V parts)

  prep_weights<<<64, 256, 0, stream>>>(W2, W1, W2L, W1L);
  orn_main<<<960, 256, 0, stream>>>(objs, b1, b2, W1L, W2L, out);
}

// Round 11
// 272.572 us; speedup vs baseline: 1.3323x; 1.0246x over previous
//
#include <hip/hip_runtime.h>

// ObjectRelationNetwork on MI355X — slab-per-block revision (240 x 1024).
//
// Budget (r10): total 279 = fill ~152 + prep ~2 + theta ~47 + orn ~78; floor ~50
// (40us store + ~10 prologue). r10 lesson: 4blk/CU residency only -5us (straggler
// blocks still saturate HBM). Remaining structural waste: the 4 q-blocks per
// (b,t) slab each redundantly computed phase1 + the same 32x256 U'/V (4x issue
// pressure, latency-heavy). This round: one 1024-thread block per slab (240
// blocks <= 256 CUs, single round, no tail). Phases 1-2 once per slab with 16
// waves; main loop: wave wid -> (q=wid>>2, ncol=(wid&3)*64) — identical per-wave
// code to r10. LDS 32KB; launch_bounds(1024,4) = same 128-VGPR cap as r10.
// Keeps (verified): fp16 MFMA (r8), barrier-free main loop (r5), plain
// back-to-back full-line stores (r9, -23us), RNE converts (r2), static acc (r6).

typedef __attribute__((ext_vector_type(8))) _Float16 f16x8;  // 8 fp16 = 4 VGPRs
typedef __attribute__((ext_vector_type(4))) float f32x4;     // MFMA C/D, stores
typedef __attribute__((ext_vector_type(4))) unsigned u32x4;
typedef __attribute__((ext_vector_type(2))) unsigned u32x2;

#define MFMA16(a, b, c) __builtin_amdgcn_mfma_f32_16x16x32_f16((a), (b), (c), 0, 0, 0)
#define E_ELEMS 62914560ull   // 240*1024*256 e floats, then 245760 all_is_obj floats

__device__ __forceinline__ short f2h(float f) {   // RNE float->fp16 (v_cvt_f16_f32)
  _Float16 h = (_Float16)f;
  return __builtin_bit_cast(short, h);
}
__device__ __forceinline__ unsigned pack2(short lo, short hi) {
  return (unsigned)(unsigned short)lo | ((unsigned)(unsigned short)hi << 16);
}

// h-fragment: relu(u+v) on 8 fp16 — 4x v_pk_add_f16 + 4x v_pk_max_f16.
__device__ __forceinline__ f16x8 hfrag(f16x8 u, f16x8 v) {
  f16x8 h = u + v;
  const f16x8 z = __builtin_bit_cast(f16x8, (u32x4){0u, 0u, 0u, 0u});
  return __builtin_elementwise_max(h, z);
}

// ---- prep: W2 (256x256) -> W2L[kb=k>>3][n][k&7]  (K=256, fragment layout, fp16)
//            W1 (256x256) -> W1L[part][kb][n][jj]  (part 0: d 0..127 (U),
//                                                   part 1: d 128..255 (V))
__global__ void prep_weights(const float* __restrict__ W2, const float* __restrict__ W1,
                             short* __restrict__ W2L, short* __restrict__ W1L) {
  int t = blockIdx.x * 256 + threadIdx.x;   // 0..16383
  const float* src;
  short* dst;
  if (t < 8192) {
    int kb = t >> 8, n = t & 255;
    src = W2 + (size_t)n * 256 + kb * 8;
    dst = W2L + (size_t)t * 8;
  } else {
    int u = t - 8192;                       // 0..8191
    int part = u >> 12, kb = (u >> 8) & 15, n = u & 255;
    src = W1 + (size_t)n * 256 + part * 128 + kb * 8;
    dst = W1L + (size_t)u * 8;
  }
  float4 x = *(const float4*)src;
  float4 y = *(const float4*)(src + 4);
  short f[8];
  f[0] = f2h(x.x); f[1] = f2h(x.y); f[2] = f2h(x.z); f[3] = f2h(x.w);
  f[4] = f2h(y.x); f[5] = f2h(y.y); f[6] = f2h(y.z); f[7] = f2h(y.w);
  u32x4 o;
  o[0] = pack2(f[0], f[1]); o[1] = pack2(f[2], f[3]);
  o[2] = pack2(f[4], f[5]); o[3] = pack2(f[6], f[7]);
  *(u32x4*)dst = o;
}

// ---- main: 240 blocks (1 per (b,t) slab), 1024 threads (16 waves). LDS 32 KB.
__global__ __launch_bounds__(1024, 4) void orn_main(
    const float* __restrict__ objs, const float* __restrict__ b1,
    const float* __restrict__ b2, const short* __restrict__ W1L,
    const short* __restrict__ W2L, float* __restrict__ out) {
  __shared__ short ULs[32 * 32 * 8];   // [kb=o>>3][i][o&7]  fp16 of U' = O@W1a^T + b1
  __shared__ short VLs[32 * 32 * 8];   // [kb][j][jj]        fp16 of V  = O@W1b^T

  float* psum  = (float*)ULs;          // phase-1 scratch aliases (dead after sync3)
  float* fclip = (float*)VLs;

  const int tid = threadIdx.x;
  const int bt  = blockIdx.x;          // 0..239
  const int b   = bt / 15;
  const int tm  = bt - b * 15;         // t-1
  const float* O = objs + (size_t)(b * 16 + tm + 1) * (32 * 128);

  const int lane = tid & 63;
  const int wid  = tid >> 6;           // wave 0..15
  const int l15  = lane & 15;
  const int quad = lane >> 4;

  // ---------------- Phase 1: fp32 row sums -> all_is_obj (1024 threads) --------
  {
    int i = tid >> 5, cc = tid & 31;   // 32 rows x 32 chunks of 4 floats
    float4 v = *(const float4*)(O + i * 128 + cc * 4);
    psum[tid] = v.x + v.y + v.z + v.w;
  }
  __syncthreads();                     // sync1
  if (tid < 32) {
    float s = 0.f;
#pragma unroll
    for (int c2 = 0; c2 < 32; c2++) s += psum[tid * 32 + c2];
    fclip[tid] = fminf(fmaxf(s, 0.f), 1.f);
  }
  __syncthreads();                     // sync2
  {
    float v = fclip[tid >> 5] * fclip[tid & 31] * (float)(tm + 1);
    out[E_ELEMS + (size_t)bt * 1024 + tid] = fminf(fmaxf(v, 0.f), 1.f);
  }

  // ------- Phase 2: U',V (32 objs x 256 hidden), 16 waves x 16-col slices -------
  // A = W1L (M = o rows), B = O (N = i cols).  D: row=quad*4+r -> o, col=l15 -> i.
  {
    const int n16 = wid * 16;          // this wave's 16-col o-slice
    // B-fragments from O: B[k = ks*32+quad*8+jj][i = ni*16+l15], fp16 RNE
    f16x8 bfr[2][4];
#pragma unroll
    for (int ni = 0; ni < 2; ni++)
#pragma unroll
      for (int ks = 0; ks < 4; ks++) {
        const float* p = O + (ni * 16 + l15) * 128 + ks * 32 + quad * 8;
        float4 x = *(const float4*)p;
        float4 y = *(const float4*)(p + 4);
        f16x8 f;
        f[0] = (_Float16)x.x; f[1] = (_Float16)x.y;
        f[2] = (_Float16)x.z; f[3] = (_Float16)x.w;
        f[4] = (_Float16)y.x; f[5] = (_Float16)y.y;
        f[6] = (_Float16)y.z; f[7] = (_Float16)y.w;
        bfr[ni][ks] = f;
      }
    const f32x4 zf = {0.f, 0.f, 0.f, 0.f};
    f32x4 aU[2], aV[2];                // [ni]
    aU[0] = zf; aU[1] = zf; aV[0] = zf; aV[1] = zf;
#pragma unroll
    for (int ks = 0; ks < 4; ks++) {
      const int kb = ks * 4 + quad;    // 0..15 (K=128 per part)
      const int n = n16 + l15;
      f16x8 au = *(const f16x8*)&W1L[(size_t)((kb << 8) + n) * 8];
      f16x8 av = *(const f16x8*)&W1L[(size_t)(4096 + (kb << 8) + n) * 8];
#pragma unroll
      for (int ni = 0; ni < 2; ni++) {
        aU[ni] = MFMA16(au, bfr[ni][ks], aU[ni]);
        aV[ni] = MFMA16(av, bfr[ni][ks], aV[ni]);
      }
    }
    __syncthreads();                   // sync3: psum/fclip reads done, safe to overwrite
    // write-out: lane holds o = n16+quad*4+r (r consecutive), i = ni*16+l15
    const int ob = n16 + quad * 4;
    const float4 bb = *(const float4*)&b1[ob];        // fold b1 into U'
    const int kb2 = ob >> 3, jo = ob & 7;             // jo in {0,4} -> 8B-aligned
#pragma unroll
    for (int ni = 0; ni < 2; ni++) {
      const int i = ni * 16 + l15;
      u32x2 uu, vv;
      uu[0] = pack2(f2h(aU[ni][0] + bb.x), f2h(aU[ni][1] + bb.y));
      uu[1] = pack2(f2h(aU[ni][2] + bb.z), f2h(aU[ni][3] + bb.w));
      vv[0] = pack2(f2h(aV[ni][0]), f2h(aV[ni][1]));
      vv[1] = pack2(f2h(aV[ni][2]), f2h(aV[ni][3]));
      *(u32x2*)&ULs[((kb2 << 5) + i) * 8 + jo] = uu;
      *(u32x2*)&VLs[((kb2 << 5) + i) * 8 + jo] = vv;
    }
  }
  __syncthreads();                     // sync4: ULs/VLs ready; NO barriers after this

  // ------------- Main loop: e = relu(h @ W2^T + b2), barrier-free -------------
  // wave wid -> (q2 = wid>>2: 256-row quarter, nm = (wid&3)*64: o-col base).
  // Per-wave code identical to r10. A = W2L (M = o), B = h in-register.
  const int q2 = wid >> 2;
  const int nm = (wid & 3) * 64;
  const int R0 = q2 * 256;
  const f32x4 zf = {0.f, 0.f, 0.f, 0.f};
  const short* Wp = W2L + (size_t)(nm + l15) * 8;   // lane-invariant part folded
#pragma unroll 1
  for (int c = 0; c < 4; c++) {        // 4 chunks of 64 pair-rows
    f32x4 acc[4][4];                   // [ms=o-tile][ns=pair-tile]
#pragma unroll
    for (int ms = 0; ms < 4; ms++)
#pragma unroll
      for (int ns = 0; ns < 4; ns++) acc[ms][ns] = zf;
    const int i0 = q2 * 8 + c * 2;     // two i-values this chunk: i0, i0+1

#pragma unroll 1
    for (int ks = 0; ks < 8; ks++) {
      const int kb = ks * 4 + quad;    // 0..31 (K=256)
      const size_t kbb = (size_t)kb << 11;            // *256*8 shorts
      const f16x8 a0 = *(const f16x8*)&Wp[kbb];
      const f16x8 a1 = *(const f16x8*)&Wp[kbb + 16 * 8];
      const f16x8 a2 = *(const f16x8*)&Wp[kbb + 32 * 8];
      const f16x8 a3 = *(const f16x8*)&Wp[kbb + 48 * 8];
      const f16x8 u0 = *(const f16x8*)&ULs[((kb << 5) + i0    ) * 8];  // quad-bcast
      const f16x8 u1 = *(const f16x8*)&ULs[((kb << 5) + i0 + 1) * 8];
      const f16x8 v0 = *(const f16x8*)&VLs[((kb << 5) + l15     ) * 8]; // 256B runs
      const f16x8 v1 = *(const f16x8*)&VLs[((kb << 5) + 16 + l15) * 8];
      {
        const f16x8 hb = hfrag(u0, v0);     // ns=0: pairs (i0, j=l15)
        acc[0][0] = MFMA16(a0, hb, acc[0][0]);
        acc[1][0] = MFMA16(a1, hb, acc[1][0]);
        acc[2][0] = MFMA16(a2, hb, acc[2][0]);
        acc[3][0] = MFMA16(a3, hb, acc[3][0]);
      }
      {
        const f16x8 hb = hfrag(u1, v0);     // ns=2: (i0+1, l15)
        acc[0][2] = MFMA16(a0, hb, acc[0][2]);
        acc[1][2] = MFMA16(a1, hb, acc[1][2]);
        acc[2][2] = MFMA16(a2, hb, acc[2][2]);
        acc[3][2] = MFMA16(a3, hb, acc[3][2]);
      }
      {
        const f16x8 hb = hfrag(u0, v1);     // ns=1: (i0, 16+l15)
        acc[0][1] = MFMA16(a0, hb, acc[0][1]);
        acc[1][1] = MFMA16(a1, hb, acc[1][1]);
        acc[2][1] = MFMA16(a2, hb, acc[2][1]);
        acc[3][1] = MFMA16(a3, hb, acc[3][1]);
      }
      {
        const f16x8 hb = hfrag(u1, v1);     // ns=3: (i0+1, 16+l15)
        acc[0][3] = MFMA16(a0, hb, acc[0][3]);
        acc[1][3] = MFMA16(a1, hb, acc[1][3]);
        acc[2][3] = MFMA16(a2, hb, acc[2][3]);
        acc[3][3] = MFMA16(a3, hb, acc[3][3]);
      }
    }

    // epilogue: bias + relu + PLAIN f32x4 stores, row-major emission so the two
    // 64B halves of each 128B line are back-to-back -> L2 combines to full-line
    // evictions (r9: -23us vs NT interleaved). Static acc indexing (r6 lesson).
    const size_t prow = (size_t)bt * 1024 + R0 + c * 64;
    const float4 bb0 = *(const float4*)&b2[nm +  0 + quad * 4];
    const float4 bb1 = *(const float4*)&b2[nm + 16 + quad * 4];
    const float4 bb2 = *(const float4*)&b2[nm + 32 + quad * 4];
    const float4 bb3 = *(const float4*)&b2[nm + 48 + quad * 4];
#pragma unroll
    for (int ns = 0; ns < 4; ns++) {
      float* rp = out + (prow + ns * 16 + l15) * 256 + nm + quad * 4;
      f32x4 r;
      r[0] = fmaxf(acc[0][ns][0] + bb0.x, 0.f);
      r[1] = fmaxf(acc[0][ns][1] + bb0.y, 0.f);
      r[2] = fmaxf(acc[0][ns][2] + bb0.z, 0.f);
      r[3] = fmaxf(acc[0][ns][3] + bb0.w, 0.f);
      *(f32x4*)(rp + 0)  = r;
      r[0] = fmaxf(acc[1][ns][0] + bb1.x, 0.f);
      r[1] = fmaxf(acc[1][ns][1] + bb1.y, 0.f);
      r[2] = fmaxf(acc[1][ns][2] + bb1.z, 0.f);
      r[3] = fmaxf(acc[1][ns][3] + bb1.w, 0.f);
      *(f32x4*)(rp + 16) = r;
      r[0] = fmaxf(acc[2][ns][0] + bb2.x, 0.f);
      r[1] = fmaxf(acc[2][ns][1] + bb2.y, 0.f);
      r[2] = fmaxf(acc[2][ns][2] + bb2.z, 0.f);
      r[3] = fmaxf(acc[2][ns][3] + bb2.w, 0.f);
      *(f32x4*)(rp + 32) = r;
      r[0] = fmaxf(acc[3][ns][0] + bb3.x, 0.f);
      r[1] = fmaxf(acc[3][ns][1] + bb3.y, 0.f);
      r[2] = fmaxf(acc[3][ns][2] + bb3.z, 0.f);
      r[3] = fmaxf(acc[3][ns][3] + bb3.w, 0.f);
      *(f32x4*)(rp + 48) = r;
    }
  }
}

extern "C" void kernel_launch(void* const* d_in, const int* in_sizes, int n_in,
                              void* d_out, int out_size, void* d_ws, size_t ws_size,
                              hipStream_t stream) {
  const float* objs = (const float*)d_in[0];
  const float* W1   = (const float*)d_in[1];
  const float* b1   = (const float*)d_in[2];
  const float* W2   = (const float*)d_in[3];
  const float* b2   = (const float*)d_in[4];
  float* out = (float*)d_out;
  short* W2L = (short*)d_ws;                 // 128 KB fp16 swizzled W2
  short* W1L = W2L + 8192 * 8;               // 128 KB fp16 swizzled W1 (U|V parts)

  prep_weights<<<64, 256, 0, stream>>>(W2, W1, W2L, W1L);
  orn_main<<<240, 1024, 0, stream>>>(objs, b1, b2, W1L, W2L, out);
}